// Round 1
// baseline (3506.162 us; speedup 1.0000x reference)
//
#include <hip/hip_runtime.h>

// ---------------------------------------------------------------------------
// RNN-KAN forward.  B=1024, Tx=64, IN0=256, H=512, TY=16, coeff=8.
// Output: y_pred (1024*16 f32) then h_all (1024*80*512 f32), flat.
// ---------------------------------------------------------------------------

using s16x8 = __attribute__((ext_vector_type(8))) short;
using u16x8 = __attribute__((ext_vector_type(8))) unsigned short;
using f32x4 = __attribute__((ext_vector_type(4))) float;

#define HALL_TSTRIDE 512
#define HALL_BSTRIDE (80 * 512)

__device__ __forceinline__ unsigned short f2bf(float f) {
  unsigned u = __builtin_bit_cast(unsigned, f);
  u += 0x7fffu + ((u >> 16) & 1u);   // round-to-nearest-even
  return (unsigned short)(u >> 16);
}
__device__ __forceinline__ float bf2f(unsigned short h) {
  unsigned u = ((unsigned)h) << 16;
  return __builtin_bit_cast(float, u);
}
__device__ __forceinline__ float silu(float x) {
  return x / (1.f + __expf(-x));
}

// 8 cubic B-spline basis values on the uniform 12-knot grid (knots g0 + j/invh).
// For x in [t_s, t_{s+1}):  nonzero are j = s-3..s with the standard uniform
// cubic values; everything else (incl. x outside the grid) is 0.
__device__ __forceinline__ void basis8_f32(float xv, float g0, float invh, float* out) {
  float u = (xv - g0) * invh;
  float fs = floorf(u);
  int s = (int)fs;
  float r = u - fs;
  float omr = 1.f - r;
  float r2 = r * r, r3 = r2 * r;
  float n0 = (1.f / 6.f) * omr * omr * omr;                  // j = s-3
  float n1 = (1.f / 6.f) * (3.f * r3 - 6.f * r2 + 4.f);      // j = s-2
  float n2 = (1.f / 6.f) * (-3.f * r3 + 3.f * r2 + 3.f * r + 1.f); // j = s-1
  float n3 = (1.f / 6.f) * r3;                               // j = s
#pragma unroll
  for (int j = 0; j < 8; ++j) {
    int d = s - j;
    out[j] = (d == 0) ? n3 : (d == 1) ? n2 : (d == 2) ? n1 : (d == 3) ? n0 : 0.f;
  }
}

__device__ __forceinline__ u16x8 basis8_bf16(float xv, float g0, float invh) {
  float t[8];
  basis8_f32(xv, g0, invh, t);
  u16x8 o;
#pragma unroll
  for (int j = 0; j < 8; ++j) o[j] = f2bf(t[j]);
  return o;
}

// ---------------------------------------------------------------------------
// Prep kernels
// ---------------------------------------------------------------------------

// W_aug[o][k] bf16: k<256 -> base_weight[o][k]; k=256+i*8+g -> sw[o][i][g]*sc[o][i]
__global__ __launch_bounds__(256) void prep_waug(const float* __restrict__ bw,
                                                 const float* __restrict__ sw,
                                                 const float* __restrict__ sc,
                                                 unsigned short* __restrict__ Waug) {
  int o = blockIdx.x;
  for (int k = threadIdx.x; k < 2304; k += 256) {
    float v;
    if (k < 256) {
      v = bw[o * 256 + k];
    } else {
      int idx = k - 256;
      int i = idx >> 3, g = idx & 7;
      v = sw[(o * 256 + i) * 8 + g] * sc[o * 256 + i];
    }
    Waug[(long)o * 2304 + k] = f2bf(v);
  }
}

__global__ __launch_bounds__(256) void prep_whh(const float* __restrict__ w,
                                                unsigned short* __restrict__ hi,
                                                unsigned short* __restrict__ lo) {
  for (int i = blockIdx.x * 256 + threadIdx.x; i < 512 * 512; i += gridDim.x * 256) {
    float v = w[i];
    unsigned short h = f2bf(v);
    hi[i] = h;
    lo[i] = f2bf(v - bf2f(h));
  }
}

__global__ __launch_bounds__(256) void prep_h0(const float* __restrict__ h0,
                                               unsigned short* __restrict__ hh,
                                               unsigned short* __restrict__ hl) {
  for (int i = blockIdx.x * 256 + threadIdx.x; i < 1024 * 512; i += gridDim.x * 256) {
    float v = h0[i];
    unsigned short h = f2bf(v);
    hh[i] = h;
    hl[i] = f2bf(v - bf2f(h));
  }
}

// i2h for x==0 (decode steps): silu(0)=0, spline part in exact f32. Also barrier init.
__global__ __launch_bounds__(256) void prep_i2hz(const float* __restrict__ sw,
                                                 const float* __restrict__ sc,
                                                 const float* __restrict__ grd,
                                                 float* __restrict__ i2hz,
                                                 unsigned* __restrict__ bar) {
  int o = blockIdx.x * 256 + threadIdx.x;
  if (o == 0) { bar[0] = 0u; bar[1] = 0u; }
  if (o < 512) {
    float g0 = grd[0];
    float invh = 1.f / (grd[1] - grd[0]);
    float bs[8];
    basis8_f32(0.f, g0, invh, bs);
    float s = 0.f;
    for (int i = 0; i < 256; ++i) {
      float a = 0.f;
#pragma unroll
      for (int j = 0; j < 8; ++j) a += bs[j] * sw[(o * 256 + i) * 8 + j];
      s += a * sc[o * 256 + i];
    }
    i2hz[o] = s;
  }
}

// ---------------------------------------------------------------------------
// Phase A: i2h GEMM.  C(65536 x 512) = A_aug(65536 x 2304) @ W_aug^T.
// Row m = b*64 + t.  Result stored (f32) into h_all[b][t][o] (encoder slots).
// A_aug columns computed on the fly: silu(x) for k<256, spline bases after.
// ---------------------------------------------------------------------------
#define A_BK 64
#define A_LD (A_BK + 8)   // pad: row stride 144 B -> 2-way-max bank aliasing

__global__ __launch_bounds__(256) void kan_i2h_gemm(const float* __restrict__ x,
                                                    const float* __restrict__ grd,
                                                    const unsigned short* __restrict__ Waug,
                                                    float* __restrict__ hall) {
  __shared__ short As[128][A_LD];
  __shared__ short Bs[128][A_LD];

  int bid = blockIdx.x;
  int mt = bid >> 2;           // 512 m-tiles
  int nt = bid & 3;            // 4 n-tiles
  int m0 = mt * 128, n0 = nt * 128;
  int tid = threadIdx.x;
  int lane = tid & 63, wave = tid >> 6;
  int wr = wave >> 1, wc = wave & 1;

  float g0 = grd[0];
  float invh = 1.f / (grd[1] - grd[0]);

  f32x4 acc[4][4] = {};

  int srow = tid >> 1, spart = tid & 1;
  const float* xrow = x + (long)(m0 + srow) * 256;
  const unsigned short* wrow = Waug + (long)(n0 + srow) * 2304;

  for (int ks = 0; ks < 36; ++ks) {
    int k0 = ks * 64;
    int kc = k0 + spart * 32;
    // stage B (W_aug, already bf16)
    {
      const u16x8* src = (const u16x8*)(wrow + kc);
      u16x8* dst = (u16x8*)&Bs[srow][spart * 32];
#pragma unroll
      for (int c = 0; c < 4; ++c) dst[c] = src[c];
    }
    // stage A (computed)
    {
      u16x8* dst = (u16x8*)&As[srow][spart * 32];
      if (k0 < 256) {
        const float* xs = xrow + kc;
#pragma unroll
        for (int c = 0; c < 4; ++c) {
          f32x4 lo = *(const f32x4*)(xs + c * 8);
          f32x4 hi = *(const f32x4*)(xs + c * 8 + 4);
          u16x8 pk;
#pragma unroll
          for (int e = 0; e < 4; ++e) {
            pk[e] = f2bf(silu(lo[e]));
            pk[e + 4] = f2bf(silu(hi[e]));
          }
          dst[c] = pk;
        }
      } else {
        int i0 = ((k0 - 256) >> 3) + spart * 4;
        f32x4 xs = *(const f32x4*)(xrow + i0);
#pragma unroll
        for (int q = 0; q < 4; ++q) dst[q] = basis8_bf16(xs[q], g0, invh);
      }
    }
    __syncthreads();
#pragma unroll
    for (int kk = 0; kk < 2; ++kk) {
      s16x8 a[4], b[4];
#pragma unroll
      for (int i = 0; i < 4; ++i)
        a[i] = *(const s16x8*)&As[wr * 64 + i * 16 + (lane & 15)][kk * 32 + (lane >> 4) * 8];
#pragma unroll
      for (int j = 0; j < 4; ++j)
        b[j] = *(const s16x8*)&Bs[wc * 64 + j * 16 + (lane & 15)][kk * 32 + (lane >> 4) * 8];
#pragma unroll
      for (int i = 0; i < 4; ++i)
#pragma unroll
        for (int j = 0; j < 4; ++j)
          acc[i][j] = __builtin_amdgcn_mfma_f32_16x16x32_bf16(a[i], b[j], acc[i][j], 0, 0, 0);
    }
    __syncthreads();
  }

  int c0 = n0 + wc * 64;
#pragma unroll
  for (int i = 0; i < 4; ++i) {
    int mbase = m0 + wr * 64 + i * 16 + ((lane >> 4) << 2);
#pragma unroll
    for (int r = 0; r < 4; ++r) {
      int m = mbase + r;
      int bb = m >> 6, tt = m & 63;
      float* orow = hall + (long)bb * HALL_BSTRIDE + (long)tt * HALL_TSTRIDE + c0;
#pragma unroll
      for (int j = 0; j < 4; ++j) orow[j * 16 + (lane & 15)] = acc[i][j][r];
    }
  }
}

// ---------------------------------------------------------------------------
// Phase B: persistent recurrent kernel, 128 blocks (co-resident on 256 CUs),
// grid barrier between the 80 steps.  Split-bf16 (h and W hi+lo, drop lo*lo).
// Step T: h = tanh(i2h_T + h_prev @ W^T + b); h_all[:,T,:] = h.
// i2h_T read from h_all[:,T,:] (phase-A values) for T<64, else i2hz const.
// ---------------------------------------------------------------------------
__device__ __forceinline__ void grid_sync(unsigned* bar) {
  __syncthreads();
  if (threadIdx.x == 0) {
    __threadfence();
    unsigned g = __hip_atomic_load(bar + 1, __ATOMIC_RELAXED, __HIP_MEMORY_SCOPE_AGENT);
    unsigned prev = __hip_atomic_fetch_add(bar, 1u, __ATOMIC_ACQ_REL, __HIP_MEMORY_SCOPE_AGENT);
    if (prev == gridDim.x - 1u) {
      __hip_atomic_store(bar, 0u, __ATOMIC_RELAXED, __HIP_MEMORY_SCOPE_AGENT);
      __hip_atomic_fetch_add(bar + 1, 1u, __ATOMIC_ACQ_REL, __HIP_MEMORY_SCOPE_AGENT);
    } else {
      while (__hip_atomic_load(bar + 1, __ATOMIC_ACQUIRE, __HIP_MEMORY_SCOPE_AGENT) == g) {
        __builtin_amdgcn_s_sleep(2);
      }
    }
  }
  __syncthreads();
}

__global__ __launch_bounds__(256) void rnn_steps(const unsigned short* __restrict__ WhhHi,
                                                 const unsigned short* __restrict__ WhhLo,
                                                 const float* __restrict__ i2hz,
                                                 const float* __restrict__ h2hb,
                                                 float* __restrict__ hall,
                                                 unsigned short* __restrict__ hbh0,
                                                 unsigned short* __restrict__ hbh1,
                                                 unsigned short* __restrict__ hbl0,
                                                 unsigned short* __restrict__ hbl1,
                                                 unsigned* __restrict__ bar) {
  __shared__ short Bs[32][520];   // Whh_hi tile: 32 output cols x 512 k (padded)

  int bid = blockIdx.x;
  int mt = bid >> 4, nt = bid & 15;   // 8 x 16 -> tiles 128 rows x 32 cols
  int m0 = mt * 128, n0 = nt * 32;
  int tid = threadIdx.x;
  int lane = tid & 63, wave = tid >> 6;

  {
    int r = tid >> 3, p = tid & 7;
    const u16x8* src = (const u16x8*)(WhhHi + (long)(n0 + r) * 512 + p * 64);
    u16x8* dst = (u16x8*)&Bs[r][p * 64];
#pragma unroll
    for (int c = 0; c < 8; ++c) dst[c] = src[c];
  }
  __syncthreads();

  int arow0 = m0 + wave * 32 + (lane & 15);
  int koff = (lane >> 4) * 8;

  for (int T = 0; T < 80; ++T) {
    const unsigned short* hph = (T & 1) ? hbh0 : hbh1;  // read hb[(T+1)&1]
    const unsigned short* hpl = (T & 1) ? hbl0 : hbl1;
    unsigned short* hwh = (T & 1) ? hbh1 : hbh0;        // write hb[T&1]
    unsigned short* hwl = (T & 1) ? hbl1 : hbl0;

    f32x4 acc[2][2] = {};
#pragma unroll 4
    for (int kk = 0; kk < 16; ++kk) {
      int kbase = kk * 32 + koff;
      s16x8 ah[2], al[2], bh[2], bl[2];
#pragma unroll
      for (int i = 0; i < 2; ++i) {
        long aoff = (long)(arow0 + i * 16) * 512 + kbase;
        ah[i] = *(const s16x8*)(hph + aoff);
        al[i] = *(const s16x8*)(hpl + aoff);
      }
#pragma unroll
      for (int j = 0; j < 2; ++j) {
        bh[j] = *(const s16x8*)&Bs[j * 16 + (lane & 15)][kbase];
        bl[j] = *(const s16x8*)(WhhLo + (long)(n0 + j * 16 + (lane & 15)) * 512 + kbase);
      }
#pragma unroll
      for (int i = 0; i < 2; ++i)
#pragma unroll
        for (int j = 0; j < 2; ++j) {
          acc[i][j] = __builtin_amdgcn_mfma_f32_16x16x32_bf16(ah[i], bh[j], acc[i][j], 0, 0, 0);
          acc[i][j] = __builtin_amdgcn_mfma_f32_16x16x32_bf16(ah[i], bl[j], acc[i][j], 0, 0, 0);
          acc[i][j] = __builtin_amdgcn_mfma_f32_16x16x32_bf16(al[i], bh[j], acc[i][j], 0, 0, 0);
        }
    }

    bool enc = (T < 64);
#pragma unroll
    for (int i = 0; i < 2; ++i) {
      int bbase = m0 + wave * 32 + i * 16 + ((lane >> 4) << 2);
#pragma unroll
      for (int r = 0; r < 4; ++r) {
        int bb = bbase + r;
        float* hall_row = hall + (long)bb * HALL_BSTRIDE + (long)T * HALL_TSTRIDE;
        const float* i2row = enc ? hall_row : i2hz;
#pragma unroll
        for (int j = 0; j < 2; ++j) {
          int o = n0 + j * 16 + (lane & 15);
          float pre = acc[i][j][r] + i2row[o] + h2hb[o];
          float h = tanhf(pre);
          hall_row[o] = h;
          unsigned short hi = f2bf(h);
          hwh[(long)bb * 512 + o] = hi;
          hwl[(long)bb * 512 + o] = f2bf(h - bf2f(hi));
        }
      }
    }
    grid_sync(bar);
  }
}

// ---------------------------------------------------------------------------
// y_pred[b][ty] = dot(h_all[b][64+ty][:], fc_w) + fc_b   (one wave per (b,ty))
// ---------------------------------------------------------------------------
__global__ __launch_bounds__(256) void y_final(const float* __restrict__ hall,
                                               const float* __restrict__ fcw,
                                               const float* __restrict__ fcb,
                                               float* __restrict__ y) {
  int gw = (blockIdx.x * 256 + threadIdx.x) >> 6;
  int lane = threadIdx.x & 63;
  int bb = gw >> 4, ty = gw & 15;
  const float* hrow = hall + (long)bb * HALL_BSTRIDE + (long)(64 + ty) * HALL_TSTRIDE;
  float s = 0.f;
#pragma unroll
  for (int c = 0; c < 8; ++c) s += hrow[lane + c * 64] * fcw[lane + c * 64];
#pragma unroll
  for (int off = 32; off > 0; off >>= 1) s += __shfl_xor(s, off);
  if (lane == 0) y[bb * 16 + ty] = s + fcb[0];
}

// ---------------------------------------------------------------------------
extern "C" void kernel_launch(void* const* d_in, const int* in_sizes, int n_in,
                              void* d_out, int out_size, void* d_ws, size_t ws_size,
                              hipStream_t stream) {
  (void)in_sizes; (void)n_in; (void)out_size; (void)ws_size;
  const float* x   = (const float*)d_in[0];
  const float* h0  = (const float*)d_in[1];
  const float* grd = (const float*)d_in[2];
  const float* bw  = (const float*)d_in[3];
  const float* sw  = (const float*)d_in[4];
  const float* sc  = (const float*)d_in[5];
  const float* whh = (const float*)d_in[6];
  const float* hbb = (const float*)d_in[7];
  const float* fcw = (const float*)d_in[8];
  const float* fcb = (const float*)d_in[9];

  float* out = (float*)d_out;
  float* ypred = out;
  float* hall = out + 1024 * 16;

  char* ws = (char*)d_ws;
  unsigned short* Waug  = (unsigned short*)(ws);                 // 512*2304*2 = 2359296
  unsigned short* WhhHi = (unsigned short*)(ws + 2359296);       // 524288
  unsigned short* WhhLo = (unsigned short*)(ws + 2883584);       // 524288
  float*          i2hz  = (float*)(ws + 3407872);                // 2048
  unsigned short* hbh0  = (unsigned short*)(ws + 3409920);       // 1048576
  unsigned short* hbh1  = (unsigned short*)(ws + 4458496);       // 1048576
  unsigned short* hbl0  = (unsigned short*)(ws + 5507072);       // 1048576
  unsigned short* hbl1  = (unsigned short*)(ws + 6555648);       // 1048576
  unsigned*       bar   = (unsigned*)(ws + 7604224);             // 2 x u32

  prep_waug<<<512, 256, 0, stream>>>(bw, sw, sc, Waug);
  prep_whh<<<512, 256, 0, stream>>>(whh, WhhHi, WhhLo);
  prep_h0<<<512, 256, 0, stream>>>(h0, hbh1, hbl1);
  prep_i2hz<<<2, 256, 0, stream>>>(sw, sc, grd, i2hz, bar);
  kan_i2h_gemm<<<2048, 256, 0, stream>>>(x, grd, Waug, hall);
  rnn_steps<<<128, 256, 0, stream>>>(WhhHi, WhhLo, i2hz, hbb, hall,
                                     hbh0, hbh1, hbl0, hbl1, bar);
  y_final<<<4096, 256, 0, stream>>>(hall, fcw, fcb, ypred);
}

// Round 2
// 3344.022 us; speedup vs baseline: 1.0485x; 1.0485x over previous
//
#include <hip/hip_runtime.h>

// ---------------------------------------------------------------------------
// RNN-KAN forward.  B=1024, Tx=64, IN0=256, H=512, TY=16, coeff=8.
// Output: y_pred (1024*16 f32) then h_all (1024*80*512 f32), flat.
// ---------------------------------------------------------------------------

using s16x8 = __attribute__((ext_vector_type(8))) short;
using u16x8 = __attribute__((ext_vector_type(8))) unsigned short;
using f32x4 = __attribute__((ext_vector_type(4))) float;

#define HALL_TSTRIDE 512
#define HALL_BSTRIDE (80 * 512)

__device__ __forceinline__ unsigned short f2bf(float f) {
  unsigned u = __builtin_bit_cast(unsigned, f);
  u += 0x7fffu + ((u >> 16) & 1u);   // round-to-nearest-even
  return (unsigned short)(u >> 16);
}
__device__ __forceinline__ float bf2f(unsigned short h) {
  unsigned u = ((unsigned)h) << 16;
  return __builtin_bit_cast(float, u);
}
__device__ __forceinline__ float silu(float x) {
  return x / (1.f + __expf(-x));
}
__device__ __forceinline__ float tanh_fast(float x) {
  float e2 = __expf(2.f * x);                    // inf/0 saturate correctly
  return 1.f - 2.f * __builtin_amdgcn_rcpf(e2 + 1.f);
}

// 8 cubic B-spline basis values on the uniform 12-knot grid.
__device__ __forceinline__ void basis8_f32(float xv, float g0, float invh, float* out) {
  float u = (xv - g0) * invh;
  float fs = floorf(u);
  int s = (int)fs;
  float r = u - fs;
  float omr = 1.f - r;
  float r2 = r * r, r3 = r2 * r;
  float n0 = (1.f / 6.f) * omr * omr * omr;
  float n1 = (1.f / 6.f) * (3.f * r3 - 6.f * r2 + 4.f);
  float n2 = (1.f / 6.f) * (-3.f * r3 + 3.f * r2 + 3.f * r + 1.f);
  float n3 = (1.f / 6.f) * r3;
#pragma unroll
  for (int j = 0; j < 8; ++j) {
    int d = s - j;
    out[j] = (d == 0) ? n3 : (d == 1) ? n2 : (d == 2) ? n1 : (d == 3) ? n0 : 0.f;
  }
}

__device__ __forceinline__ u16x8 basis8_bf16(float xv, float g0, float invh) {
  float t[8];
  basis8_f32(xv, g0, invh, t);
  u16x8 o;
#pragma unroll
  for (int j = 0; j < 8; ++j) o[j] = f2bf(t[j]);
  return o;
}

// ---------------------------------------------------------------------------
// Prep kernels
// ---------------------------------------------------------------------------
__global__ __launch_bounds__(256) void prep_waug(const float* __restrict__ bw,
                                                 const float* __restrict__ sw,
                                                 const float* __restrict__ sc,
                                                 unsigned short* __restrict__ Waug) {
  int o = blockIdx.x;
  for (int k = threadIdx.x; k < 2304; k += 256) {
    float v;
    if (k < 256) {
      v = bw[o * 256 + k];
    } else {
      int idx = k - 256;
      int i = idx >> 3, g = idx & 7;
      v = sw[(o * 256 + i) * 8 + g] * sc[o * 256 + i];
    }
    Waug[(long)o * 2304 + k] = f2bf(v);
  }
}

__global__ __launch_bounds__(256) void prep_whh(const float* __restrict__ w,
                                                unsigned short* __restrict__ hi,
                                                unsigned short* __restrict__ lo) {
  for (int i = blockIdx.x * 256 + threadIdx.x; i < 512 * 512; i += gridDim.x * 256) {
    float v = w[i];
    unsigned short h = f2bf(v);
    hi[i] = h;
    lo[i] = f2bf(v - bf2f(h));
  }
}

__global__ __launch_bounds__(256) void prep_i2hz(const float* __restrict__ sw,
                                                 const float* __restrict__ sc,
                                                 const float* __restrict__ grd,
                                                 float* __restrict__ i2hz) {
  int o = blockIdx.x * 256 + threadIdx.x;
  if (o < 512) {
    float g0 = grd[0];
    float invh = 1.f / (grd[1] - grd[0]);
    float bs[8];
    basis8_f32(0.f, g0, invh, bs);
    float s = 0.f;
    for (int i = 0; i < 256; ++i) {
      float a = 0.f;
#pragma unroll
      for (int j = 0; j < 8; ++j) a += bs[j] * sw[(o * 256 + i) * 8 + j];
      s += a * sc[o * 256 + i];
    }
    i2hz[o] = s;
  }
}

// ---------------------------------------------------------------------------
// Phase A: i2h GEMM.  C(65536 x 512) = A_aug(65536 x 2304) @ W_aug^T.
// 1024 blocks x 512 threads; tile 128m x 256n; 8 waves as 2x4 (64x64 each).
// ---------------------------------------------------------------------------
#define A_LD 72

__global__ __launch_bounds__(512) void kan_i2h_gemm(const float* __restrict__ x,
                                                    const float* __restrict__ grd,
                                                    const unsigned short* __restrict__ Waug,
                                                    float* __restrict__ hall) {
  __shared__ short As[128][A_LD];
  __shared__ short Bs[256][A_LD];

  int bid = blockIdx.x;
  int mt = bid >> 1;           // 512 m-tiles
  int nt = bid & 1;            // 2 n-tiles
  int m0 = mt * 128, n0 = nt * 256;
  int tid = threadIdx.x;
  int lane = tid & 63, wave = tid >> 6;   // 8 waves
  int wr = wave >> 2, wc = wave & 3;      // 2 x 4

  float g0 = grd[0];
  float invh = 1.f / (grd[1] - grd[0]);

  f32x4 acc[4][4] = {};

  int arow = tid >> 2, apart = tid & 3;   // A: 128 rows x 4 parts x 16k
  int brow = tid >> 1, bpart = tid & 1;   // B: 256 rows x 2 parts x 32k
  const float* xrow = x + (long)(m0 + arow) * 256;
  const unsigned short* wrow = Waug + (long)(n0 + brow) * 2304;

  for (int ks = 0; ks < 36; ++ks) {
    int k0 = ks * 64;
    // stage B (W_aug, bf16): 4 x u16x8 per thread
    {
      const u16x8* src = (const u16x8*)(wrow + k0 + bpart * 32);
      u16x8* dst = (u16x8*)&Bs[brow][bpart * 32];
#pragma unroll
      for (int c = 0; c < 4; ++c) dst[c] = src[c];
    }
    // stage A (computed): 16 k per thread -> 2 x u16x8
    {
      u16x8* dst = (u16x8*)&As[arow][apart * 16];
      int kA = k0 + apart * 16;
      if (k0 < 256) {
        const float* xs = xrow + kA;
#pragma unroll
        for (int c = 0; c < 2; ++c) {
          f32x4 v0 = *(const f32x4*)(xs + c * 8);
          f32x4 v1 = *(const f32x4*)(xs + c * 8 + 4);
          u16x8 pk;
#pragma unroll
          for (int e = 0; e < 4; ++e) {
            pk[e] = f2bf(silu(v0[e]));
            pk[e + 4] = f2bf(silu(v1[e]));
          }
          dst[c] = pk;
        }
      } else {
        int i0 = (kA - 256) >> 3;
        dst[0] = basis8_bf16(xrow[i0], g0, invh);
        dst[1] = basis8_bf16(xrow[i0 + 1], g0, invh);
      }
    }
    __syncthreads();
#pragma unroll
    for (int kk = 0; kk < 2; ++kk) {
      s16x8 a[4], b[4];
#pragma unroll
      for (int i = 0; i < 4; ++i)
        a[i] = *(const s16x8*)&As[wr * 64 + i * 16 + (lane & 15)][kk * 32 + (lane >> 4) * 8];
#pragma unroll
      for (int j = 0; j < 4; ++j)
        b[j] = *(const s16x8*)&Bs[wc * 64 + j * 16 + (lane & 15)][kk * 32 + (lane >> 4) * 8];
#pragma unroll
      for (int i = 0; i < 4; ++i)
#pragma unroll
        for (int j = 0; j < 4; ++j)
          acc[i][j] = __builtin_amdgcn_mfma_f32_16x16x32_bf16(a[i], b[j], acc[i][j], 0, 0, 0);
    }
    __syncthreads();
  }

  int c0 = n0 + wc * 64;
#pragma unroll
  for (int i = 0; i < 4; ++i) {
    int mbase = m0 + wr * 64 + i * 16 + ((lane >> 4) << 2);
#pragma unroll
    for (int r = 0; r < 4; ++r) {
      int m = mbase + r;
      int bb = m >> 6, tt = m & 63;
      float* orow = hall + (long)bb * HALL_BSTRIDE + (long)tt * HALL_TSTRIDE + c0;
#pragma unroll
      for (int j = 0; j < 4; ++j) orow[j * 16 + (lane & 15)] = acc[i][j][r];
    }
  }
}

// ---------------------------------------------------------------------------
// Phase B: batch-parallel persistent recurrence. 64 blocks x 512 threads.
// Block owns 16 batch rows; h lives in registers (split-bf16 A-frags);
// Whh hi+lo streamed from L2 to B-frags each step; NO grid sync at all.
// Cross-wave h redistribution via 32 KB XOR-swizzled LDS + 2 local barriers.
// ---------------------------------------------------------------------------
__global__ __launch_bounds__(512, 2) void rnn_persist(
    const unsigned short* __restrict__ WhhHi,
    const unsigned short* __restrict__ WhhLo,
    const float* __restrict__ i2hz,
    const float* __restrict__ h2hb,
    const float* __restrict__ h0,
    float* __restrict__ hall) {
  __shared__ __align__(16) unsigned short hH[16 * 512];
  __shared__ __align__(16) unsigned short hL[16 * 512];

  const int tid = threadIdx.x;
  const int lane = tid & 63;
  const int wave = tid >> 6;           // 0..7, owns output cols wave*64..+64
  const int m0 = blockIdx.x * 16;      // batch rows
  const int n0w = wave * 64;
  const int colg = lane & 15;          // A-row / C-col selector
  const int kgrp = lane >> 4;          // 0..3
  const int crow = kgrp * 4;           // C-row base

  const int abase0 = colg * 1024 + kgrp * 16;     // LDS byte addr (pre-swizzle)
  const int aswz = (colg & 7) << 4;

  // initial A fragments from h0 (f32 -> bf16 hi/lo)
  s16x8 ah[16], al[16];
#pragma unroll
  for (int kk = 0; kk < 16; ++kk) {
    const float* src = h0 + (long)(m0 + colg) * 512 + kk * 32 + kgrp * 8;
    f32x4 v0 = *(const f32x4*)src;
    f32x4 v1 = *(const f32x4*)(src + 4);
    u16x8 hi, lo;
#pragma unroll
    for (int e = 0; e < 4; ++e) {
      unsigned short h1 = f2bf(v0[e]); hi[e] = h1; lo[e] = f2bf(v0[e] - bf2f(h1));
      unsigned short h2 = f2bf(v1[e]); hi[e + 4] = h2; lo[e + 4] = f2bf(v1[e] - bf2f(h2));
    }
    ah[kk] = __builtin_bit_cast(s16x8, hi);
    al[kk] = __builtin_bit_cast(s16x8, lo);
  }

  int wb[4];
  float bias_j[4], i2z_j[4];
#pragma unroll
  for (int j = 0; j < 4; ++j) {
    int o = n0w + j * 16 + colg;
    wb[j] = o * 512 + kgrp * 8;
    bias_j[j] = h2hb[o];
    i2z_j[j] = i2hz[o];
  }

  for (int T = 0; T < 80; ++T) {
    const bool enc = (T < 64);
    // prefetch i2h (lands under the MFMA loop)
    float i2v[4][4];
#pragma unroll
    for (int r = 0; r < 4; ++r) {
      const float* hrow = hall + (long)(m0 + crow + r) * HALL_BSTRIDE + (long)T * HALL_TSTRIDE;
#pragma unroll
      for (int j = 0; j < 4; ++j)
        i2v[r][j] = enc ? hrow[n0w + j * 16 + colg] : i2z_j[j];
    }

    f32x4 acc[4] = {};
#pragma unroll
    for (int kk = 0; kk < 16; ++kk) {
      s16x8 bh[4], bl[4];
#pragma unroll
      for (int j = 0; j < 4; ++j) {
        bh[j] = *(const s16x8*)(WhhHi + wb[j] + kk * 32);
        bl[j] = *(const s16x8*)(WhhLo + wb[j] + kk * 32);
      }
#pragma unroll
      for (int j = 0; j < 4; ++j) {
        acc[j] = __builtin_amdgcn_mfma_f32_16x16x32_bf16(ah[kk], bh[j], acc[j], 0, 0, 0);
        acc[j] = __builtin_amdgcn_mfma_f32_16x16x32_bf16(ah[kk], bl[j], acc[j], 0, 0, 0);
        acc[j] = __builtin_amdgcn_mfma_f32_16x16x32_bf16(al[kk], bh[j], acc[j], 0, 0, 0);
      }
    }

    // epilogue: tanh, write h_all (f32) + LDS (bf16 hi/lo, swizzled)
#pragma unroll
    for (int r = 0; r < 4; ++r) {
      const int row = crow + r;
      float* hrow = hall + (long)(m0 + row) * HALL_BSTRIDE + (long)T * HALL_TSTRIDE;
#pragma unroll
      for (int j = 0; j < 4; ++j) {
        const int o = n0w + j * 16 + colg;
        float pre = acc[j][r] + i2v[r][j] + bias_j[j];
        float h = tanh_fast(pre);
        hrow[o] = h;
        unsigned short hh = f2bf(h);
        unsigned short hl = f2bf(h - bf2f(hh));
        int boff = (row * 1024 + o * 2) ^ ((row & 7) << 4);
        *(unsigned short*)((char*)hH + boff) = hh;
        *(unsigned short*)((char*)hL + boff) = hl;
      }
    }
    __syncthreads();
    // reload A-frags (full 512-col h) from LDS
#pragma unroll
    for (int kk = 0; kk < 16; ++kk) {
      int off = (abase0 + kk * 64) ^ aswz;
      ah[kk] = *(const s16x8*)((const char*)hH + off);
      al[kk] = *(const s16x8*)((const char*)hL + off);
    }
    __syncthreads();
  }
}

// ---------------------------------------------------------------------------
// y_pred[b][ty] = dot(h_all[b][64+ty][:], fc_w) + fc_b   (one wave per (b,ty))
// ---------------------------------------------------------------------------
__global__ __launch_bounds__(256) void y_final(const float* __restrict__ hall,
                                               const float* __restrict__ fcw,
                                               const float* __restrict__ fcb,
                                               float* __restrict__ y) {
  int gw = (blockIdx.x * 256 + threadIdx.x) >> 6;
  int lane = threadIdx.x & 63;
  int bb = gw >> 4, ty = gw & 15;
  const float* hrow = hall + (long)bb * HALL_BSTRIDE + (long)(64 + ty) * HALL_TSTRIDE;
  float s = 0.f;
#pragma unroll
  for (int c = 0; c < 8; ++c) s += hrow[lane + c * 64] * fcw[lane + c * 64];
#pragma unroll
  for (int off = 32; off > 0; off >>= 1) s += __shfl_xor(s, off);
  if (lane == 0) y[bb * 16 + ty] = s + fcb[0];
}

// ---------------------------------------------------------------------------
extern "C" void kernel_launch(void* const* d_in, const int* in_sizes, int n_in,
                              void* d_out, int out_size, void* d_ws, size_t ws_size,
                              hipStream_t stream) {
  (void)in_sizes; (void)n_in; (void)out_size; (void)ws_size;
  const float* x   = (const float*)d_in[0];
  const float* h0  = (const float*)d_in[1];
  const float* grd = (const float*)d_in[2];
  const float* bw  = (const float*)d_in[3];
  const float* sw  = (const float*)d_in[4];
  const float* sc  = (const float*)d_in[5];
  const float* whh = (const float*)d_in[6];
  const float* hbb = (const float*)d_in[7];
  const float* fcw = (const float*)d_in[8];
  const float* fcb = (const float*)d_in[9];

  float* out = (float*)d_out;
  float* ypred = out;
  float* hall = out + 1024 * 16;

  char* ws = (char*)d_ws;
  unsigned short* Waug  = (unsigned short*)(ws);                 // 2359296 B
  unsigned short* WhhHi = (unsigned short*)(ws + 2359296);       // 524288 B
  unsigned short* WhhLo = (unsigned short*)(ws + 2883584);       // 524288 B
  float*          i2hz  = (float*)(ws + 3407872);                // 2048 B

  prep_waug<<<512, 256, 0, stream>>>(bw, sw, sc, Waug);
  prep_whh<<<512, 256, 0, stream>>>(whh, WhhHi, WhhLo);
  prep_i2hz<<<2, 256, 0, stream>>>(sw, sc, grd, i2hz);
  kan_i2h_gemm<<<1024, 512, 0, stream>>>(x, grd, Waug, hall);
  rnn_persist<<<64, 512, 0, stream>>>(WhhHi, WhhLo, i2hz, hbb, h0, hall);
  y_final<<<4096, 256, 0, stream>>>(hall, fcw, fcb, ypred);
}